// Round 5
// baseline (225.207 us; speedup 1.0000x reference)
//
#include <hip/hip_runtime.h>
#include <hip/hip_cooperative_groups.h>

namespace cg = cooperative_groups;

// Problem constants (reference: T=4096, N_ENVS=2048, fp32)
#define TT    4096
#define NENV  2048
#define N4    (NENV / 4)          // float4 columns = 512
#define L     8                   // timesteps per chunk
#define NCH   (TT / L)            // 512 chunks
#define NCGRP 2                   // blocks per chunk (512 float4-cols / 256 thr)
#define NBLK  (NCH * NCGRP)       // 1024 blocks = 4 blocks/CU

#define GAMMA 0.99f
#define GL    (0.99f * 0.95f)

#define STEP_AB(r_, v_, nv_, dn_, A_, B_)                    \
    {                                                        \
        const float nd = (dn_) ? 0.0f : 1.0f;                \
        const float di = (r_) + GAMMA * (nv_) * nd - (v_);   \
        const float c  = GL * nd;                            \
        (B_) = di + c * (B_);                                \
        (A_) = c * (A_);                                     \
    }

#define STEP_OUT(r_, v_, nv_, dn_, g_, adv_, ret_)           \
    {                                                        \
        const float nd = (dn_) ? 0.0f : 1.0f;                \
        const float di = (r_) + GAMMA * (nv_) * nd - (v_);   \
        (g_) = di + GL * nd * (g_);                          \
        (adv_) = (g_);                                       \
        (ret_) = (g_) + (v_);                                \
    }

// ---------------- Fused cooperative kernel (no per-thread arrays) ----------
__global__ __launch_bounds__(256, 4) void gae_coop(
    const float4* __restrict__ r4,
    const float4* __restrict__ v4,
    const float4* __restrict__ nv4,
    const int4*   __restrict__ dn4,
    float4* __restrict__ adv4,
    float4* __restrict__ ret4,
    float4* __restrict__ wsA,     // [NCH][N4]
    float4* __restrict__ wsB,     // [NCH][N4]
    float*  __restrict__ gIn)     // [NCH][NENV]
{
    const int chunk = blockIdx.x / NCGRP;                       // 0..511
    const int c4    = (blockIdx.x % NCGRP) * 256 + threadIdx.x; // 0..511
    const int t0    = chunk * L;

    // ---- Phase 1: stream inputs once, per-chunk affine g_{t0}=B+A*g_{t0+L} ----
    {
        float Ax = 1.0f, Ay = 1.0f, Az = 1.0f, Aw = 1.0f;
        float Bx = 0.0f, By = 0.0f, Bz = 0.0f, Bw = 0.0f;
#pragma unroll
        for (int i = L - 1; i >= 0; --i) {
            const int idx = (t0 + i) * N4 + c4;                 // 16B/lane coalesced
            const float4 r  = r4[idx];
            const float4 v  = v4[idx];
            const float4 nv = nv4[idx];
            const int4   dn = dn4[idx];
            STEP_AB(r.x, v.x, nv.x, dn.x, Ax, Bx);
            STEP_AB(r.y, v.y, nv.y, dn.y, Ay, By);
            STEP_AB(r.z, v.z, nv.z, dn.z, Az, Bz);
            STEP_AB(r.w, v.w, nv.w, dn.w, Aw, Bw);
        }
        wsA[chunk * N4 + c4] = make_float4(Ax, Ay, Az, Aw);
        wsB[chunk * N4 + c4] = make_float4(Bx, By, Bz, Bw);
    }

    cg::this_grid().sync();

    // ---- Phase 2: serial suffix scan over chunks, 2048 threads (8 blocks) ----
    if (blockIdx.x < NENV / 256) {
        const int col = blockIdx.x * 256 + threadIdx.x;
        const float* a = (const float*)wsA;
        const float* b = (const float*)wsB;
        float g = 0.0f;
#pragma unroll 8
        for (int j = NCH - 1; j >= 0; --j) {
            gIn[j * NENV + col] = g;
            g = b[j * NENV + col] + a[j * NENV + col] * g;
        }
    }

    cg::this_grid().sync();

    // ---- Phase 3: replay recurrence (inputs L3-warm), write adv & returns ----
    {
        const float4 g0 = ((const float4*)gIn)[chunk * N4 + c4];
        float gx = g0.x, gy = g0.y, gz = g0.z, gw = g0.w;
#pragma unroll
        for (int i = L - 1; i >= 0; --i) {
            const int idx = (t0 + i) * N4 + c4;
            const float4 r  = r4[idx];
            const float4 v  = v4[idx];
            const float4 nv = nv4[idx];
            const int4   dn = dn4[idx];
            float4 a, t;
            STEP_OUT(r.x, v.x, nv.x, dn.x, gx, a.x, t.x);
            STEP_OUT(r.y, v.y, nv.y, dn.y, gy, a.y, t.y);
            STEP_OUT(r.z, v.z, nv.z, dn.z, gz, a.z, t.z);
            STEP_OUT(r.w, v.w, nv.w, dn.w, gw, a.w, t.w);
            adv4[idx] = a;
            ret4[idx] = t;
        }
    }
}

// ---------------- Non-cooperative 3-kernel fallback (round-4, proven) ------
__global__ __launch_bounds__(256) void gae_k1(
    const float4* __restrict__ r4, const float4* __restrict__ v4,
    const float4* __restrict__ nv4, const int4* __restrict__ dn4,
    float4* __restrict__ wsA, float4* __restrict__ wsB)
{
    const int chunk = blockIdx.x / NCGRP;
    const int c4    = (blockIdx.x % NCGRP) * 256 + threadIdx.x;
    const int t0    = chunk * L;
    float Ax = 1.0f, Ay = 1.0f, Az = 1.0f, Aw = 1.0f;
    float Bx = 0.0f, By = 0.0f, Bz = 0.0f, Bw = 0.0f;
#pragma unroll
    for (int i = L - 1; i >= 0; --i) {
        const int idx = (t0 + i) * N4 + c4;
        const float4 r  = r4[idx];
        const float4 v  = v4[idx];
        const float4 nv = nv4[idx];
        const int4   dn = dn4[idx];
        STEP_AB(r.x, v.x, nv.x, dn.x, Ax, Bx);
        STEP_AB(r.y, v.y, nv.y, dn.y, Ay, By);
        STEP_AB(r.z, v.z, nv.z, dn.z, Az, Bz);
        STEP_AB(r.w, v.w, nv.w, dn.w, Aw, Bw);
    }
    wsA[chunk * N4 + c4] = make_float4(Ax, Ay, Az, Aw);
    wsB[chunk * N4 + c4] = make_float4(Bx, By, Bz, Bw);
}

__global__ __launch_bounds__(256) void gae_k2(
    const float* __restrict__ wsA, const float* __restrict__ wsB,
    float* __restrict__ gIn)
{
    const int col = blockIdx.x * 256 + threadIdx.x;
    float g = 0.0f;
#pragma unroll 8
    for (int j = NCH - 1; j >= 0; --j) {
        gIn[j * NENV + col] = g;
        g = wsB[j * NENV + col] + wsA[j * NENV + col] * g;
    }
}

__global__ __launch_bounds__(256) void gae_k3(
    const float4* __restrict__ r4, const float4* __restrict__ v4,
    const float4* __restrict__ nv4, const int4* __restrict__ dn4,
    const float4* __restrict__ gIn4, float4* __restrict__ adv4,
    float4* __restrict__ ret4)
{
    const int chunk = blockIdx.x / NCGRP;
    const int c4    = (blockIdx.x % NCGRP) * 256 + threadIdx.x;
    const int t0    = chunk * L;
    const float4 g0 = gIn4[chunk * N4 + c4];
    float gx = g0.x, gy = g0.y, gz = g0.z, gw = g0.w;
#pragma unroll
    for (int i = L - 1; i >= 0; --i) {
        const int idx = (t0 + i) * N4 + c4;
        const float4 r  = r4[idx];
        const float4 v  = v4[idx];
        const float4 nv = nv4[idx];
        const int4   dn = dn4[idx];
        float4 a, t;
        STEP_OUT(r.x, v.x, nv.x, dn.x, gx, a.x, t.x);
        STEP_OUT(r.y, v.y, nv.y, dn.y, gy, a.y, t.y);
        STEP_OUT(r.z, v.z, nv.z, dn.z, gz, a.z, t.z);
        STEP_OUT(r.w, v.w, nv.w, dn.w, gw, a.w, t.w);
        adv4[idx] = a;
        ret4[idx] = t;
    }
}

extern "C" void kernel_launch(void* const* d_in, const int* in_sizes, int n_in,
                              void* d_out, int out_size, void* d_ws, size_t ws_size,
                              hipStream_t stream) {
    const float4* r4  = (const float4*)d_in[0];
    const float4* v4  = (const float4*)d_in[1];
    const float4* nv4 = (const float4*)d_in[2];
    const int4*   dn4 = (const int4*)d_in[3];

    float4* adv4 = (float4*)d_out;
    float4* ret4 = adv4 + (size_t)TT * N4;

    float4* wsA = (float4*)d_ws;                    // 4 MiB
    float4* wsB = wsA + (size_t)NCH * N4;           // 4 MiB
    float*  gIn = (float*)(wsB + (size_t)NCH * N4); // 4 MiB

    int blocksPerCU = 0;
    (void)hipOccupancyMaxActiveBlocksPerMultiprocessor(
        &blocksPerCU, (const void*)gae_coop, 256, 0);
    const bool coop_ok = (blocksPerCU * 256 >= NBLK);

    bool launched = false;
    if (coop_ok) {
        void* args[] = {
            (void*)&r4, (void*)&v4, (void*)&nv4, (void*)&dn4,
            (void*)&adv4, (void*)&ret4, (void*)&wsA, (void*)&wsB, (void*)&gIn
        };
        hipError_t e = hipLaunchCooperativeKernel((const void*)gae_coop,
                                                  dim3(NBLK), dim3(256),
                                                  args, 0, stream);
        launched = (e == hipSuccess);
    }
    if (!launched) {
        gae_k1<<<NBLK, 256, 0, stream>>>(r4, v4, nv4, dn4, wsA, wsB);
        gae_k2<<<NENV / 256, 256, 0, stream>>>((const float*)wsA,
                                               (const float*)wsB, gIn);
        gae_k3<<<NBLK, 256, 0, stream>>>(r4, v4, nv4, dn4, (const float4*)gIn,
                                         adv4, ret4);
    }
}

// Round 6
// 204.245 us; speedup vs baseline: 1.1026x; 1.1026x over previous
//
#include <hip/hip_runtime.h>

// Problem constants (reference: T=4096, N_ENVS=2048, fp32)
#define TT    4096
#define NENV  2048
#define N4    (NENV / 4)          // float4 columns = 512
#define L     8                   // timesteps per chunk
#define NCH   (TT / L)            // 512 chunks
#define NCGRP 2                   // blocks per chunk (512 f4cols / 256 thr)
#define NBLK  (NCH * NCGRP)       // 1024 blocks
#define SUP   8                   // chunks per superchunk
#define NSUP  (NCH / SUP)         // 64 superchunks

#define GAMMA 0.99f
#define GL    (0.99f * 0.95f)

#define STEP_AB(r_, v_, nv_, dn_, A_, B_)                    \
    {                                                        \
        const float nd = (dn_) ? 0.0f : 1.0f;                \
        const float di = (r_) + GAMMA * (nv_) * nd - (v_);   \
        const float c  = GL * nd;                            \
        (B_) = di + c * (B_);                                \
        (A_) = c * (A_);                                     \
    }

#define STEP_OUT(r_, v_, nv_, dn_, g_, adv_, ret_)           \
    {                                                        \
        const float nd = (dn_) ? 0.0f : 1.0f;                \
        const float di = (r_) + GAMMA * (nv_) * nd - (v_);   \
        (g_) = di + GL * nd * (g_);                          \
        (adv_) = (g_);                                       \
        (ret_) = (g_) + (v_);                                \
    }

// compose: apply chunk j BELOW current accumulated (A',B'):
//   A' <- A_j * A' ; B' <- B_j + A_j * B'   (iterate j high -> low)
#define COMPOSE(Aj_, Bj_, A_, B_)                            \
    {                                                        \
        (B_) = (Bj_) + (Aj_) * (B_);                         \
        (A_) = (Aj_) * (A_);                                 \
    }

// ---- k1: per-chunk affine (A,B), streaming inputs once (float4) ----
__global__ __launch_bounds__(256) void gae_k1(
    const float4* __restrict__ r4,  const float4* __restrict__ v4,
    const float4* __restrict__ nv4, const int4*   __restrict__ dn4,
    float4* __restrict__ wsA, float4* __restrict__ wsB)
{
    const int chunk = blockIdx.x / NCGRP;
    const int c4    = (blockIdx.x % NCGRP) * 256 + threadIdx.x;
    const int t0    = chunk * L;

    float Ax = 1.0f, Ay = 1.0f, Az = 1.0f, Aw = 1.0f;
    float Bx = 0.0f, By = 0.0f, Bz = 0.0f, Bw = 0.0f;
#pragma unroll
    for (int i = L - 1; i >= 0; --i) {
        const int idx = (t0 + i) * N4 + c4;
        const float4 r  = r4[idx];
        const float4 v  = v4[idx];
        const float4 nv = nv4[idx];
        const int4   dn = dn4[idx];
        STEP_AB(r.x, v.x, nv.x, dn.x, Ax, Bx);
        STEP_AB(r.y, v.y, nv.y, dn.y, Ay, By);
        STEP_AB(r.z, v.z, nv.z, dn.z, Az, Bz);
        STEP_AB(r.w, v.w, nv.w, dn.w, Aw, Bw);
    }
    wsA[chunk * N4 + c4] = make_float4(Ax, Ay, Az, Aw);
    wsB[chunk * N4 + c4] = make_float4(Bx, By, Bz, Bw);
}

// ---- k2a: compose 8 chunk-affines -> one super-affine (parallel) ----
__global__ __launch_bounds__(256) void gae_k2a(
    const float4* __restrict__ wsA, const float4* __restrict__ wsB,
    float4* __restrict__ supA, float4* __restrict__ supB)
{
    const int t  = blockIdx.x * 256 + threadIdx.x;   // 0 .. NSUP*N4-1
    const int s  = t >> 9;                           // / N4
    const int c4 = t & (N4 - 1);

    float Ax = 1.0f, Ay = 1.0f, Az = 1.0f, Aw = 1.0f;
    float Bx = 0.0f, By = 0.0f, Bz = 0.0f, Bw = 0.0f;
#pragma unroll
    for (int j = s * SUP + SUP - 1; j >= s * SUP; --j) {   // high -> low
        const float4 Aj = wsA[j * N4 + c4];
        const float4 Bj = wsB[j * N4 + c4];
        COMPOSE(Aj.x, Bj.x, Ax, Bx);
        COMPOSE(Aj.y, Bj.y, Ay, By);
        COMPOSE(Aj.z, Bj.z, Az, Bz);
        COMPOSE(Aj.w, Bj.w, Aw, Bw);
    }
    supA[s * N4 + c4] = make_float4(Ax, Ay, Az, Aw);
    supB[s * N4 + c4] = make_float4(Bx, By, Bz, Bw);
}

// ---- k2b: serial scan over 64 superchunks per column (tiny) ----
__global__ __launch_bounds__(64) void gae_k2b(
    const float* __restrict__ supA, const float* __restrict__ supB,
    float* __restrict__ gSup)      // [NSUP][NENV]: g entering each super
{
    const int col = blockIdx.x * 64 + threadIdx.x;   // 2048 threads, 32 blocks
    float g = 0.0f;
#pragma unroll 8
    for (int s = NSUP - 1; s >= 0; --s) {
        gSup[s * NENV + col] = g;
        g = supB[s * NENV + col] + supA[s * NENV + col] * g;
    }
}

// ---- k3: derive chunk's incoming g (<=7 composes), replay, write outputs ----
__global__ __launch_bounds__(256) void gae_k3(
    const float4* __restrict__ r4,  const float4* __restrict__ v4,
    const float4* __restrict__ nv4, const int4*   __restrict__ dn4,
    const float4* __restrict__ wsA, const float4* __restrict__ wsB,
    const float4* __restrict__ gSup4,   // [NSUP][N4]
    float4* __restrict__ adv4, float4* __restrict__ ret4)
{
    const int chunk = blockIdx.x / NCGRP;
    const int c4    = (blockIdx.x % NCGRP) * 256 + threadIdx.x;
    const int s     = chunk / SUP;
    const int t0    = chunk * L;

    // g entering this chunk = (compose of chunks chunk+1 .. s*SUP+SUP-1) (gSup[s])
    const float4 g0 = gSup4[s * N4 + c4];
    float gx = g0.x, gy = g0.y, gz = g0.z, gw = g0.w;
    for (int j = s * SUP + SUP - 1; j > chunk; --j) {    // high -> low
        const float4 Aj = wsA[j * N4 + c4];
        const float4 Bj = wsB[j * N4 + c4];
        gx = Bj.x + Aj.x * gx;
        gy = Bj.y + Aj.y * gy;
        gz = Bj.z + Aj.z * gz;
        gw = Bj.w + Aj.w * gw;
    }

#pragma unroll
    for (int i = L - 1; i >= 0; --i) {
        const int idx = (t0 + i) * N4 + c4;
        const float4 r  = r4[idx];
        const float4 v  = v4[idx];
        const float4 nv = nv4[idx];
        const int4   dn = dn4[idx];
        float4 a, t;
        STEP_OUT(r.x, v.x, nv.x, dn.x, gx, a.x, t.x);
        STEP_OUT(r.y, v.y, nv.y, dn.y, gy, a.y, t.y);
        STEP_OUT(r.z, v.z, nv.z, dn.z, gz, a.z, t.z);
        STEP_OUT(r.w, v.w, nv.w, dn.w, gw, a.w, t.w);
        adv4[idx] = a;
        ret4[idx] = t;
    }
}

extern "C" void kernel_launch(void* const* d_in, const int* in_sizes, int n_in,
                              void* d_out, int out_size, void* d_ws, size_t ws_size,
                              hipStream_t stream) {
    const float4* r4  = (const float4*)d_in[0];
    const float4* v4  = (const float4*)d_in[1];
    const float4* nv4 = (const float4*)d_in[2];
    const int4*   dn4 = (const int4*)d_in[3];

    float4* adv4 = (float4*)d_out;
    float4* ret4 = adv4 + (size_t)TT * N4;

    float4* wsA  = (float4*)d_ws;                    // NCH*N4*16  = 4 MiB
    float4* wsB  = wsA  + (size_t)NCH * N4;          // 4 MiB
    float4* supA = wsB  + (size_t)NCH * N4;          // NSUP*N4*16 = 512 KiB
    float4* supB = supA + (size_t)NSUP * N4;         // 512 KiB
    float4* gSup = supB + (size_t)NSUP * N4;         // 512 KiB

    gae_k1<<<NBLK, 256, 0, stream>>>(r4, v4, nv4, dn4, wsA, wsB);
    gae_k2a<<<(NSUP * N4) / 256, 256, 0, stream>>>(wsA, wsB, supA, supB);
    gae_k2b<<<NENV / 64, 64, 0, stream>>>((const float*)supA, (const float*)supB,
                                          (float*)gSup);
    gae_k3<<<NBLK, 256, 0, stream>>>(r4, v4, nv4, dn4, wsA, wsB,
                                     (const float4*)gSup, adv4, ret4);
}